// Round 1
// baseline (719.673 us; speedup 1.0000x reference)
//
#include <hip/hip_runtime.h>
#include <hip/hip_cooperative_groups.h>

namespace cg = cooperative_groups;

#define DD 256        // D
#define SS 256        // S
#define BB 64         // B
#define NEDGE 500000  // E
#define MM 2048       // M
#define NEG_INF -10000000000.0f
#define ROWF4 512     // float4 stride between consecutive (b,s) type rows in token_reprs
#define NROWS (BB * SS)  // 16384

// edge kernel geometry: co-resident cooperative grid
#define EPB 512                              // edges per block
#define NBLK ((NEDGE + EPB - 1) / EPB)       // 977 blocks <= 4/CU * 256 CU

// workspace byte offsets
#define OFF_VC     0
#define OFF_MSORT  4096
#define OFF_BSTART (4096 + MM * 4)
#define OFF_ASLAB  (1 << 16)
#define OFF_P2     ((1 << 16) + (8 << 20))
#define OFF_MROWS  ((1 << 16) + (16 << 20))

__device__ __forceinline__ float bflo(unsigned u) { return __uint_as_float(u << 16); }
__device__ __forceinline__ float bfhi(unsigned u) { return __uint_as_float(u & 0xFFFF0000u); }
__device__ __forceinline__ unsigned short bf_rne(float f) {
    unsigned u = __float_as_uint(f);
    return (unsigned short)((u + 0x7FFFu + ((u >> 16) & 1u)) >> 16);
}
__device__ __forceinline__ unsigned pack2_rne(float a, float b) {
    return (unsigned)bf_rne(a) | ((unsigned)bf_rne(b) << 16);
}

// block 0: vc[d] = sum_j w1[d,j]*w2[j], vc[256] = b1.w2+b2  (wave-per-row, coalesced)
// block 1: counting-sort m by batch pointer
__global__ void setup_k(const float* __restrict__ w1, const float* __restrict__ b1,
                        const float* __restrict__ w2, const float* __restrict__ b2,
                        const int* __restrict__ bp,
                        float* __restrict__ vc, int* __restrict__ msorted,
                        int* __restrict__ bstart) {
    const int t = threadIdx.x;
    if (blockIdx.x == 0) {
        __shared__ float sw2[DD / 2];
        if (t < DD / 2) sw2[t] = w2[t];
        __syncthreads();
        const int lane = t & 63, w = t >> 6;
        for (int r = w; r < DD; r += 4) {
            float x = w1[r * (DD / 2) + lane] * sw2[lane]
                    + w1[r * (DD / 2) + 64 + lane] * sw2[64 + lane];
            x += __shfl_down(x, 32);
            x += __shfl_down(x, 16);
            x += __shfl_down(x, 8);
            x += __shfl_down(x, 4);
            x += __shfl_down(x, 2);
            x += __shfl_down(x, 1);
            if (lane == 0) vc[r] = x;
        }
        if (w == 0) {
            float x = b1[lane] * sw2[lane] + b1[64 + lane] * sw2[64 + lane];
            x += __shfl_down(x, 32);
            x += __shfl_down(x, 16);
            x += __shfl_down(x, 8);
            x += __shfl_down(x, 4);
            x += __shfl_down(x, 2);
            x += __shfl_down(x, 1);
            if (lane == 0) vc[DD] = x + b2[0];
        }
    } else {
        __shared__ int hist[BB];
        __shared__ int offs[BB + 1];
        if (t < BB) hist[t] = 0;
        __syncthreads();
        for (int m = t; m < MM; m += 256) atomicAdd(&hist[bp[m]], 1);
        __syncthreads();
        if (t == 0) {
            int acc = 0;
            for (int i = 0; i < BB; ++i) { offs[i] = acc; acc += hist[i]; }
            offs[BB] = acc;
        }
        __syncthreads();
        if (t < BB + 1) bstart[t] = offs[t];
        __syncthreads();
        for (int m = t; m < MM; m += 256) {
            int pos = atomicAdd(&offs[bp[m]], 1);
            msorted[pos] = m;
        }
    }
}

// Compact strided fp32 rows into dense bf16 tables:
//  blocks [0, NROWS/4): type rows -> aslab (slice-major, SINGLE shared table)
//                       + P2 (row-major, for lm staging)
//  blocks [NROWS/4, +MM/4): mask rows via lm_indices -> mrows (row-major)
__global__ __launch_bounds__(256) void compact(
        const float* __restrict__ tok, const int* __restrict__ lmi,
        unsigned* __restrict__ aslab,
        unsigned* __restrict__ p2, unsigned* __restrict__ mrows) {
    const int lane = threadIdx.x & 63;
    const int w    = threadIdx.x >> 6;
    if (blockIdx.x < NROWS / 4) {
        const int row = blockIdx.x * 4 + w;
        const float4 a = ((const float4*)tok)[(size_t)row * ROWF4 + lane];
        unsigned p0 = pack2_rne(a.x, a.y), p1 = pack2_rne(a.z, a.w);
        const int k = lane >> 3, sub = lane & 7;
        const size_t si = (size_t)(k * NROWS + row) * 16 + sub * 2;
        aslab[si] = p0; aslab[si + 1] = p1;
        const size_t pi = (size_t)row * 128 + lane * 2;
        p2[pi] = p0; p2[pi + 1] = p1;
    } else {
        const int m = (blockIdx.x - NROWS / 4) * 4 + w;
        const float4 a = ((const float4*)(tok + (size_t)lmi[m] * DD))[lane];
        mrows[(size_t)m * 128 + lane * 2]     = pack2_rne(a.x, a.y);
        mrows[(size_t)m * 128 + lane * 2 + 1] = pack2_rne(a.z, a.w);
    }
}

// Fused edge kernel, COOPERATIVE version: co-resident grid, accumulators in
// registers across the whole k-loop, grid.sync() every 2 slices so all blocks
// gather from the same ~2MB of the table at a time -> per-XCD-L2 resident,
// no slice thrash from inter-block drift.
__global__ __launch_bounds__(256, 4) void edge_fused(
        const unsigned* __restrict__ aslab,
        const int* __restrict__ edges, const float* __restrict__ vc,
        float* __restrict__ out) {
    cg::grid_group grid = cg::this_grid();
    const int t = threadIdx.x;
    const int lane = t & 63, w = t >> 6;
    const int sub = lane & 7, j = lane >> 3;
    const int e0 = blockIdx.x * EPB;
    __shared__ int sIdx[2][EPB];
    __shared__ float accs[EPB];
    for (int f = t; f < EPB; f += 256) {
        const int e = e0 + f;
        const bool val = e < NEDGE;
        sIdx[0][f] = val ? __builtin_nontemporal_load(edges + e) : 0;
        sIdx[1][f] = val ? __builtin_nontemporal_load(edges + NEDGE + e) : 0;
    }
    __syncthreads();

    float acc[16];
    #pragma unroll
    for (int i = 0; i < 16; ++i) acc[i] = 0.f;
    const int slotbase = w * 8 + j;  // + i*32

    #pragma unroll 1
    for (int k = 0; k < 8; ++k) {
        const unsigned* base = aslab + (size_t)k * (NROWS * 16) + sub * 2;
        const float4 v = ((const float4*)vc)[k * 8 + sub];
        #pragma unroll
        for (int i = 0; i < 16; ++i) {
            const int slot = i * 32 + slotbase;
            const int sc = sIdx[0][slot];
            const int gl = sIdx[1][slot];
            const uint2 pu = *(const uint2*)(base + (size_t)sc * 16);
            const uint2 qu = *(const uint2*)(base + (size_t)gl * 16);
            acc[i] += (bflo(pu.x) * bflo(qu.x)) * v.x
                    + (bfhi(pu.x) * bfhi(qu.x)) * v.y
                    + (bflo(pu.y) * bflo(qu.y)) * v.z
                    + (bfhi(pu.y) * bfhi(qu.y)) * v.w;
        }
        if ((k & 1) && k < 7) grid.sync();   // phase-lock slice pairs
    }

    #pragma unroll
    for (int i = 0; i < 16; ++i) {
        float p = acc[i];
        p += __shfl_down(p, 4, 8);
        p += __shfl_down(p, 2, 8);
        p += __shfl_down(p, 1, 8);
        if (sub == 0) accs[i * 32 + slotbase] = p;
    }
    __syncthreads();
    const float c = vc[DD];
    for (int f = t; f < EPB; f += 256) {
        const int e = e0 + f;
        if (e < NEDGE) __builtin_nontemporal_store(accs[f] + c, out + e);
    }
}

// Per-batch grouped lm GEMM with masked-column skip; A and B staged from
// dense bf16 tables.
__global__ __launch_bounds__(256) void lm_gemm(
        const unsigned* __restrict__ p2,
        const unsigned* __restrict__ mrows,
        const int* __restrict__ msorted,
        const int* __restrict__ bstart,
        const int* __restrict__ tpm,
        float* __restrict__ out) {
    const int b  = blockIdx.x;
    const int st = blockIdx.y;   // 64-wide s tile
    const int ch = blockIdx.z;   // mask chunk
    const int s0 = bstart[b], s1 = bstart[b + 1];
    const int base = s0 + ch * 32;
    if (base >= s1) return;
    const int nm = min(32, s1 - base);
    const int t = threadIdx.x;

    __shared__ unsigned lmaskU[32 * 132];
    __shared__ unsigned srowU[32 * 132];
    __shared__ int mids[32];
    __shared__ int sact[64];
    __shared__ int snact;

    if (t < 32) mids[t] = msorted[base + min(t, nm - 1)];
    if (t >= 64 && t < 128) {  // wave 1: ballot-compact active columns
        int lt = t - 64;
        bool act = tpm[b * SS + st * 64 + lt] != 0;
        unsigned long long mk = __ballot(act);
        if (act) sact[__popcll(mk & ((1ull << lt) - 1))] = lt;
        if (lt == 0) snact = (int)__popcll(mk);
    }
    __syncthreads();

    for (int f = t; f < nm * 32; f += 256) {
        int r = f >> 5, q = f & 31;
        *(uint4*)&lmaskU[r * 132 + q * 4] = ((const uint4*)mrows)[(size_t)mids[r] * 32 + q];
    }
    for (int f = t; f < nm * 64; f += 256) {
        int i = f >> 6, c = f & 63;
        if (!tpm[b * SS + st * 64 + c])
            out[(size_t)mids[i] * SS + st * 64 + c] = NEG_INF;
    }
    __syncthreads();

    const int nact = snact;
    const int i2 = t & 15, sg = t >> 4;

    for (int g = 0; g * 32 < nact; ++g) {
        if (g) __syncthreads();
        const int nv = min(32, nact - g * 32);
        for (int f = t; f < nv * 32; f += 256) {
            int r = f >> 5, q = f & 31;
            size_t row = (size_t)b * SS + st * 64 + sact[g * 32 + r];
            *(uint4*)&srowU[r * 132 + q * 4] = ((const uint4*)p2)[row * 32 + q];
        }
        __syncthreads();

        float a00 = 0.f, a01 = 0.f, a10 = 0.f, a11 = 0.f;
        #pragma unroll 4
        for (int stp = 0; stp < 32; ++stp) {
            const uint4 A0 = *(const uint4*)&lmaskU[i2 * 132 + stp * 4];
            const uint4 A1 = *(const uint4*)&lmaskU[(i2 + 16) * 132 + stp * 4];
            const uint4 B0 = *(const uint4*)&srowU[sg * 132 + stp * 4];
            const uint4 B1 = *(const uint4*)&srowU[(sg + 16) * 132 + stp * 4];
            float a0[8], a1[8], b0[8], b1[8];
            a0[0] = bflo(A0.x); a0[1] = bfhi(A0.x); a0[2] = bflo(A0.y); a0[3] = bfhi(A0.y);
            a0[4] = bflo(A0.z); a0[5] = bfhi(A0.z); a0[6] = bflo(A0.w); a0[7] = bfhi(A0.w);
            a1[0] = bflo(A1.x); a1[1] = bfhi(A1.x); a1[2] = bflo(A1.y); a1[3] = bfhi(A1.y);
            a1[4] = bflo(A1.z); a1[5] = bfhi(A1.z); a1[6] = bflo(A1.w); a1[7] = bfhi(A1.w);
            b0[0] = bflo(B0.x); b0[1] = bfhi(B0.x); b0[2] = bflo(B0.y); b0[3] = bfhi(B0.y);
            b0[4] = bflo(B0.z); b0[5] = bfhi(B0.z); b0[6] = bflo(B0.w); b0[7] = bfhi(B0.w);
            b1[0] = bflo(B1.x); b1[1] = bfhi(B1.x); b1[2] = bflo(B1.y); b1[3] = bfhi(B1.y);
            b1[4] = bflo(B1.z); b1[5] = bfhi(B1.z); b1[6] = bflo(B1.w); b1[7] = bfhi(B1.w);
            #pragma unroll
            for (int jj = 0; jj < 8; ++jj) {
                a00 = fmaf(a0[jj], b0[jj], a00);
                a01 = fmaf(a0[jj], b1[jj], a01);
                a10 = fmaf(a1[jj], b0[jj], a10);
                a11 = fmaf(a1[jj], b1[jj], a11);
            }
        }

        const int iA = g * 32 + sg, iB = iA + 16;
        if (i2 < nm) {
            size_t ob = (size_t)mids[i2] * SS + st * 64;
            if (iA < nact) out[ob + sact[iA]] = a00;
            if (iB < nact) out[ob + sact[iB]] = a01;
        }
        if (i2 + 16 < nm) {
            size_t ob = (size_t)mids[i2 + 16] * SS + st * 64;
            if (iA < nact) out[ob + sact[iA]] = a10;
            if (iB < nact) out[ob + sact[iB]] = a11;
        }
    }
}

extern "C" void kernel_launch(void* const* d_in, const int* in_sizes, int n_in,
                              void* d_out, int out_size, void* d_ws, size_t ws_size,
                              hipStream_t stream) {
    const float* tok = (const float*)d_in[0];
    const float* w1  = (const float*)d_in[1];
    const float* b1  = (const float*)d_in[2];
    const float* w2  = (const float*)d_in[3];
    const float* b2  = (const float*)d_in[4];
    const int* edges = (const int*)d_in[5];
    const int* lmi   = (const int*)d_in[6];
    const int* bp    = (const int*)d_in[7];
    const int* tpm   = (const int*)d_in[8];

    float* out_lemmas = (float*)d_out;
    float* out_lm     = (float*)d_out + NEDGE;

    char* ws = (char*)d_ws;
    float* vc        = (float*)(ws + OFF_VC);
    int* msorted     = (int*)(ws + OFF_MSORT);
    int* bstart      = (int*)(ws + OFF_BSTART);
    unsigned* aslab  = (unsigned*)(ws + OFF_ASLAB);
    unsigned* p2     = (unsigned*)(ws + OFF_P2);
    unsigned* mrows  = (unsigned*)(ws + OFF_MROWS);

    setup_k<<<2, 256, 0, stream>>>(w1, b1, w2, b2, bp, vc, msorted, bstart);
    compact<<<NROWS / 4 + MM / 4, 256, 0, stream>>>(tok, lmi, aslab, p2, mrows);

    {
        const unsigned* a0 = aslab;
        const int*      a1 = edges;
        const float*    a2 = vc;
        float*          a3 = out_lemmas;
        void* args[4] = { (void*)&a0, (void*)&a1, (void*)&a2, (void*)&a3 };
        hipLaunchCooperativeKernel((const void*)edge_fused, dim3(NBLK), dim3(256),
                                   args, 0, stream);
    }

    lm_gemm<<<dim3(BB, 4, 8), 256, 0, stream>>>(p2, mrows, msorted, bstart, tpm, out_lm);
}

// Round 3
// 287.716 us; speedup vs baseline: 2.5013x; 2.5013x over previous
//
#include <hip/hip_runtime.h>

#define DD 256        // D
#define SS 256        // S
#define BB 64         // B
#define NEDGE 500000  // E
#define MM 2048       // M
#define NEG_INF -10000000000.0f
#define ROWF4 512     // float4 stride between consecutive (b,s) type rows in token_reprs
#define NROWS (BB * SS)  // 16384

// edge kernel geometry: XCD-partitioned slice groups, free-running grid
#define EPB0 256
#define NCHUNK ((NEDGE + EPB0 - 1) / EPB0)   // 1954 (even)
#define NBLK_E (8 * (NCHUNK / 2))            // 7816
#define PPAD 500224                          // NEDGE padded to 256-multiple

// workspace byte offsets (ws is 512 MB per harness poison fills)
#define OFF_VC     0
#define OFF_MSORT  4096
#define OFF_BSTART (4096 + MM * 4)
#define OFF_ASLAB  (1 << 16)
#define OFF_P2     ((1 << 16) + (8 << 20))
#define OFF_MROWS  ((1 << 16) + (16 << 20))
#define OFF_PART   ((1 << 16) + (17 << 20))  // 4 x PPAD floats ~ 7.6 MB

typedef float vf4 __attribute__((ext_vector_type(4)));  // native vector for nontemporal builtins

__device__ __forceinline__ float bflo(unsigned u) { return __uint_as_float(u << 16); }
__device__ __forceinline__ float bfhi(unsigned u) { return __uint_as_float(u & 0xFFFF0000u); }
__device__ __forceinline__ unsigned short bf_rne(float f) {
    unsigned u = __float_as_uint(f);
    return (unsigned short)((u + 0x7FFFu + ((u >> 16) & 1u)) >> 16);
}
__device__ __forceinline__ unsigned pack2_rne(float a, float b) {
    return (unsigned)bf_rne(a) | ((unsigned)bf_rne(b) << 16);
}

// block 0: vc[d] = sum_j w1[d,j]*w2[j], vc[256] = b1.w2+b2  (wave-per-row, coalesced)
// block 1: counting-sort m by batch pointer
__global__ void setup_k(const float* __restrict__ w1, const float* __restrict__ b1,
                        const float* __restrict__ w2, const float* __restrict__ b2,
                        const int* __restrict__ bp,
                        float* __restrict__ vc, int* __restrict__ msorted,
                        int* __restrict__ bstart) {
    const int t = threadIdx.x;
    if (blockIdx.x == 0) {
        __shared__ float sw2[DD / 2];
        if (t < DD / 2) sw2[t] = w2[t];
        __syncthreads();
        const int lane = t & 63, w = t >> 6;
        for (int r = w; r < DD; r += 4) {
            float x = w1[r * (DD / 2) + lane] * sw2[lane]
                    + w1[r * (DD / 2) + 64 + lane] * sw2[64 + lane];
            x += __shfl_down(x, 32);
            x += __shfl_down(x, 16);
            x += __shfl_down(x, 8);
            x += __shfl_down(x, 4);
            x += __shfl_down(x, 2);
            x += __shfl_down(x, 1);
            if (lane == 0) vc[r] = x;
        }
        if (w == 0) {
            float x = b1[lane] * sw2[lane] + b1[64 + lane] * sw2[64 + lane];
            x += __shfl_down(x, 32);
            x += __shfl_down(x, 16);
            x += __shfl_down(x, 8);
            x += __shfl_down(x, 4);
            x += __shfl_down(x, 2);
            x += __shfl_down(x, 1);
            if (lane == 0) vc[DD] = x + b2[0];
        }
    } else {
        __shared__ int hist[BB];
        __shared__ int offs[BB + 1];
        if (t < BB) hist[t] = 0;
        __syncthreads();
        for (int m = t; m < MM; m += 256) atomicAdd(&hist[bp[m]], 1);
        __syncthreads();
        if (t == 0) {
            int acc = 0;
            for (int i = 0; i < BB; ++i) { offs[i] = acc; acc += hist[i]; }
            offs[BB] = acc;
        }
        __syncthreads();
        if (t < BB + 1) bstart[t] = offs[t];
        __syncthreads();
        for (int m = t; m < MM; m += 256) {
            int pos = atomicAdd(&offs[bp[m]], 1);
            msorted[pos] = m;
        }
    }
}

// Compact strided fp32 rows into dense bf16 tables:
//  blocks [0, NROWS/4): type rows -> aslab (slice-major) + P2 (row-major)
//  blocks [NROWS/4, +MM/4): mask rows via lm_indices -> mrows (row-major)
__global__ __launch_bounds__(256) void compact(
        const float* __restrict__ tok, const int* __restrict__ lmi,
        unsigned* __restrict__ aslab,
        unsigned* __restrict__ p2, unsigned* __restrict__ mrows) {
    const int lane = threadIdx.x & 63;
    const int w    = threadIdx.x >> 6;
    if (blockIdx.x < NROWS / 4) {
        const int row = blockIdx.x * 4 + w;
        const float4 a = ((const float4*)tok)[(size_t)row * ROWF4 + lane];
        unsigned p0 = pack2_rne(a.x, a.y), p1 = pack2_rne(a.z, a.w);
        const int k = lane >> 3, sub = lane & 7;
        const size_t si = (size_t)(k * NROWS + row) * 16 + sub * 2;
        aslab[si] = p0; aslab[si + 1] = p1;
        const size_t pi = (size_t)row * 128 + lane * 2;
        p2[pi] = p0; p2[pi + 1] = p1;
    } else {
        const int m = (blockIdx.x - NROWS / 4) * 4 + w;
        const float4 a = ((const float4*)(tok + (size_t)lmi[m] * DD))[lane];
        mrows[(size_t)m * 128 + lane * 2]     = pack2_rne(a.x, a.y);
        mrows[(size_t)m * 128 + lane * 2 + 1] = pack2_rne(a.z, a.w);
    }
}

// XCD-partitioned edge kernel: block -> XCD via blockIdx%8 (empirical round-
// robin). XCD pair {2p,2p+1} handles ONLY slice-pair p (2MB of the 8MB table)
// for its half of the edge chunks -> per-XCD working set 2MB, L2-resident for
// the whole kernel, no synchronization, free-running full-occupancy grid.
// Partial sums (2 slices each) go to pp[p][e]; combine() reduces.
__global__ __launch_bounds__(256) void edge_part(
        const unsigned* __restrict__ aslab,
        const int* __restrict__ edges, const float* __restrict__ vc,
        float* __restrict__ pp) {
    const int b = blockIdx.x;
    const int xcd = b & 7;
    const int p = xcd >> 1;                       // slice-pair 0..3
    const int chunk = (b >> 3) * 2 + (xcd & 1);   // 0..NCHUNK-1
    const int e0 = chunk * EPB0;
    const int k0 = p * 2;

    const int t = threadIdx.x;
    const int lane = t & 63, w = t >> 6;
    const int sub = lane & 7, j = lane >> 3;
    __shared__ int sIdx[2][EPB0];
    __shared__ float accs[EPB0];
    const int e = e0 + t;
    const bool val = e < NEDGE;
    sIdx[0][t] = val ? __builtin_nontemporal_load(edges + e) : 0;
    sIdx[1][t] = val ? __builtin_nontemporal_load(edges + NEDGE + e) : 0;

    // per-lane v for the 2 owned slices: dims k*32 + sub*4 .. +4
    const float4 v0 = ((const float4*)vc)[k0 * 8 + sub];
    const float4 v1 = ((const float4*)vc)[(k0 + 1) * 8 + sub];
    __syncthreads();

    float acc[8];
    #pragma unroll
    for (int i = 0; i < 8; ++i) acc[i] = 0.f;
    const int slotbase = w * 64 + j;  // + i*8

    // hoist row byte-offsets out of the k loop
    int offS[8], offG[8];
    #pragma unroll
    for (int i = 0; i < 8; ++i) {
        const int slot = slotbase + i * 8;
        offS[i] = sIdx[0][slot] * 16;
        offG[i] = sIdx[1][slot] * 16;
    }

    #pragma unroll 1
    for (int kk = 0; kk < 2; ++kk) {
        const int k = k0 + kk;
        const unsigned* base = aslab + (size_t)k * (NROWS * 16) + sub * 2;
        const float4 v = kk ? v1 : v0;
        #pragma unroll
        for (int i = 0; i < 8; ++i) {
            const uint2 pu = *(const uint2*)(base + offS[i]);
            const uint2 qu = *(const uint2*)(base + offG[i]);
            acc[i] += (bflo(pu.x) * bflo(qu.x)) * v.x
                    + (bfhi(pu.x) * bfhi(qu.x)) * v.y
                    + (bflo(pu.y) * bflo(qu.y)) * v.z
                    + (bfhi(pu.y) * bfhi(qu.y)) * v.w;
        }
    }
    #pragma unroll
    for (int i = 0; i < 8; ++i) {
        float x = acc[i];
        x += __shfl_down(x, 4, 8);
        x += __shfl_down(x, 2, 8);
        x += __shfl_down(x, 1, 8);
        if (sub == 0) accs[slotbase + i * 8] = x;
    }
    __syncthreads();
    if (val) pp[(size_t)p * PPAD + e] = accs[t];
}

// out[e] = vc[DD] + sum_p pp[p][e], vectorized float4
__global__ __launch_bounds__(256) void combine(
        const float* __restrict__ pp, const float* __restrict__ vc,
        float* __restrict__ out) {
    const int i = blockIdx.x * 256 + threadIdx.x;
    if (i >= NEDGE / 4) return;
    const float c = vc[DD];
    vf4 a = ((const vf4*)pp)[i];
    vf4 b = ((const vf4*)(pp + PPAD))[i];
    vf4 d = ((const vf4*)(pp + 2 * (size_t)PPAD))[i];
    vf4 e = ((const vf4*)(pp + 3 * (size_t)PPAD))[i];
    vf4 r = a + b + d + e + c;
    __builtin_nontemporal_store(r, (vf4*)out + i);
}

// Per-batch grouped lm GEMM with masked-column skip; A and B staged from
// dense bf16 tables.
__global__ __launch_bounds__(256) void lm_gemm(
        const unsigned* __restrict__ p2,
        const unsigned* __restrict__ mrows,
        const int* __restrict__ msorted,
        const int* __restrict__ bstart,
        const int* __restrict__ tpm,
        float* __restrict__ out) {
    const int b  = blockIdx.x;
    const int st = blockIdx.y;   // 64-wide s tile
    const int ch = blockIdx.z;   // mask chunk
    const int s0 = bstart[b], s1 = bstart[b + 1];
    const int base = s0 + ch * 32;
    if (base >= s1) return;
    const int nm = min(32, s1 - base);
    const int t = threadIdx.x;

    __shared__ unsigned lmaskU[32 * 132];
    __shared__ unsigned srowU[32 * 132];
    __shared__ int mids[32];
    __shared__ int sact[64];
    __shared__ int snact;

    if (t < 32) mids[t] = msorted[base + min(t, nm - 1)];
    if (t >= 64 && t < 128) {  // wave 1: ballot-compact active columns
        int lt = t - 64;
        bool act = tpm[b * SS + st * 64 + lt] != 0;
        unsigned long long mk = __ballot(act);
        if (act) sact[__popcll(mk & ((1ull << lt) - 1))] = lt;
        if (lt == 0) snact = (int)__popcll(mk);
    }
    __syncthreads();

    for (int f = t; f < nm * 32; f += 256) {
        int r = f >> 5, q = f & 31;
        *(uint4*)&lmaskU[r * 132 + q * 4] = ((const uint4*)mrows)[(size_t)mids[r] * 32 + q];
    }
    for (int f = t; f < nm * 64; f += 256) {
        int i = f >> 6, c = f & 63;
        if (!tpm[b * SS + st * 64 + c])
            out[(size_t)mids[i] * SS + st * 64 + c] = NEG_INF;
    }
    __syncthreads();

    const int nact = snact;
    const int i2 = t & 15, sg = t >> 4;

    for (int g = 0; g * 32 < nact; ++g) {
        if (g) __syncthreads();
        const int nv = min(32, nact - g * 32);
        for (int f = t; f < nv * 32; f += 256) {
            int r = f >> 5, q = f & 31;
            size_t row = (size_t)b * SS + st * 64 + sact[g * 32 + r];
            *(uint4*)&srowU[r * 132 + q * 4] = ((const uint4*)p2)[row * 32 + q];
        }
        __syncthreads();

        float a00 = 0.f, a01 = 0.f, a10 = 0.f, a11 = 0.f;
        #pragma unroll 4
        for (int stp = 0; stp < 32; ++stp) {
            const uint4 A0 = *(const uint4*)&lmaskU[i2 * 132 + stp * 4];
            const uint4 A1 = *(const uint4*)&lmaskU[(i2 + 16) * 132 + stp * 4];
            const uint4 B0 = *(const uint4*)&srowU[sg * 132 + stp * 4];
            const uint4 B1 = *(const uint4*)&srowU[(sg + 16) * 132 + stp * 4];
            float a0[8], a1[8], b0[8], b1[8];
            a0[0] = bflo(A0.x); a0[1] = bfhi(A0.x); a0[2] = bflo(A0.y); a0[3] = bfhi(A0.y);
            a0[4] = bflo(A0.z); a0[5] = bfhi(A0.z); a0[6] = bflo(A0.w); a0[7] = bfhi(A0.w);
            a1[0] = bflo(A1.x); a1[1] = bfhi(A1.x); a1[2] = bflo(A1.y); a1[3] = bfhi(A1.y);
            a1[4] = bflo(A1.z); a1[5] = bfhi(A1.z); a1[6] = bflo(A1.w); a1[7] = bfhi(A1.w);
            b0[0] = bflo(B0.x); b0[1] = bfhi(B0.x); b0[2] = bflo(B0.y); b0[3] = bfhi(B0.y);
            b0[4] = bflo(B0.z); b0[5] = bfhi(B0.z); b0[6] = bflo(B0.w); b0[7] = bfhi(B0.w);
            b1[0] = bflo(B1.x); b1[1] = bfhi(B1.x); b1[2] = bflo(B1.y); b1[3] = bfhi(B1.y);
            b1[4] = bflo(B1.z); b1[5] = bfhi(B1.z); b1[6] = bflo(B1.w); b1[7] = bfhi(B1.w);
            #pragma unroll
            for (int jj = 0; jj < 8; ++jj) {
                a00 = fmaf(a0[jj], b0[jj], a00);
                a01 = fmaf(a0[jj], b1[jj], a01);
                a10 = fmaf(a1[jj], b0[jj], a10);
                a11 = fmaf(a1[jj], b1[jj], a11);
            }
        }

        const int iA = g * 32 + sg, iB = iA + 16;
        if (i2 < nm) {
            size_t ob = (size_t)mids[i2] * SS + st * 64;
            if (iA < nact) out[ob + sact[iA]] = a00;
            if (iB < nact) out[ob + sact[iB]] = a01;
        }
        if (i2 + 16 < nm) {
            size_t ob = (size_t)mids[i2 + 16] * SS + st * 64;
            if (iA < nact) out[ob + sact[iA]] = a10;
            if (iB < nact) out[ob + sact[iB]] = a11;
        }
    }
}

extern "C" void kernel_launch(void* const* d_in, const int* in_sizes, int n_in,
                              void* d_out, int out_size, void* d_ws, size_t ws_size,
                              hipStream_t stream) {
    const float* tok = (const float*)d_in[0];
    const float* w1  = (const float*)d_in[1];
    const float* b1  = (const float*)d_in[2];
    const float* w2  = (const float*)d_in[3];
    const float* b2  = (const float*)d_in[4];
    const int* edges = (const int*)d_in[5];
    const int* lmi   = (const int*)d_in[6];
    const int* bp    = (const int*)d_in[7];
    const int* tpm   = (const int*)d_in[8];

    float* out_lemmas = (float*)d_out;
    float* out_lm     = (float*)d_out + NEDGE;

    char* ws = (char*)d_ws;
    float* vc        = (float*)(ws + OFF_VC);
    int* msorted     = (int*)(ws + OFF_MSORT);
    int* bstart      = (int*)(ws + OFF_BSTART);
    unsigned* aslab  = (unsigned*)(ws + OFF_ASLAB);
    unsigned* p2     = (unsigned*)(ws + OFF_P2);
    unsigned* mrows  = (unsigned*)(ws + OFF_MROWS);
    float* pp        = (float*)(ws + OFF_PART);

    setup_k<<<2, 256, 0, stream>>>(w1, b1, w2, b2, bp, vc, msorted, bstart);
    compact<<<NROWS / 4 + MM / 4, 256, 0, stream>>>(tok, lmi, aslab, p2, mrows);
    edge_part<<<NBLK_E, 256, 0, stream>>>(aslab, edges, vc, pp);
    combine<<<(NEDGE / 4 + 255) / 256, 256, 0, stream>>>(pp, vc, out_lemmas);
    lm_gemm<<<dim3(BB, 4, 8), 256, 0, stream>>>(p2, mrows, msorted, bstart, tpm, out_lm);
}